// Round 14
// baseline (343.157 us; speedup 1.0000x reference)
//
#include <hip/hip_runtime.h>
#include <hip/hip_bf16.h>

// VQ-VAE forward, B=64, F=16.  ALL I/O float32 (d_out = float*: decoded 4194304 f32, indices 262144 f32).
// ws layout: f1 (64 MiB) | f2 (16 MiB) | f3 (16 MiB) = 96 MiB.
// R14: NAMED-SCALAR accumulators/patches (macro-expanded) in conv2/res/tconv1.
//      R13 proved VGPR=28/32 was NOT an occupancy clamp (launch_bounds(256,2) no-op) ->
//      arrays were alloca'd to scratch (partial unroll -> runtime index). Named scalars kill the alloca.
// Lessons: pressure must fit requested budget (R7); stage once barrier once (R8);
//          uniform weights -> SGPR not LDS (R10); arrays under deep unrolls go to scratch -> name them (R14).

#define R16(M) M(0) M(1) M(2) M(3) M(4) M(5) M(6) M(7) M(8) M(9) M(10) M(11) M(12) M(13) M(14) M(15)

// ---------------- conv1: 1->16, 256->128 ----------------
__global__ __launch_bounds__(256) void conv1_k(const float* __restrict__ x, const float* __restrict__ w,
                                               const float* __restrict__ bias, float* __restrict__ out) {
    int idx = blockIdx.x * 256 + threadIdx.x;   // 64*128*128
    int ox = idx & 127;
    int oy = (idx >> 7) & 127;
    int b  = idx >> 14;
    const float* xin = x + (size_t)b * 65536;
    float pv[16];
#pragma unroll
    for (int ky = 0; ky < 4; ++ky) {
        int iy = 2 * oy - 1 + ky;
#pragma unroll
        for (int kx = 0; kx < 4; ++kx) {
            int ix = 2 * ox - 1 + kx;
            pv[ky * 4 + kx] = (iy >= 0 && iy < 256 && ix >= 0 && ix < 256)
                                  ? xin[iy * 256 + ix] : 0.f;
        }
    }
    float* o = out + (size_t)b * (16 * 16384) + oy * 128 + ox;
#pragma unroll
    for (int oc = 0; oc < 16; ++oc) {
        float acc = bias[oc];
#pragma unroll
        for (int k = 0; k < 16; ++k) acc = fmaf(pv[k], w[oc * 16 + k], acc);
        o[oc * 16384] = fmaxf(acc, 0.f);
    }
}

// ---------------- conv2: 16->16, 128->64 — named scalars ----------------
__global__ __launch_bounds__(256, 2) void conv2_k(const float* __restrict__ in, const float* __restrict__ w,
                                                  const float* __restrict__ bias, float* __restrict__ out) {
    int idx = blockIdx.x * 256 + threadIdx.x;   // 64*64*64
    int ox = idx & 63;
    int oy = (idx >> 6) & 63;
    int b  = idx >> 12;
    const float* xin = in + (size_t)b * (16 * 16384);
#define DECLA(i) float a##i = bias[i];
    R16(DECLA)
#undef DECLA
    int iy0 = 2 * oy - 1, ix0 = 2 * ox - 1;
    bool y0ok = (iy0 >= 0), y3ok = (iy0 + 3 < 128);   // middle rows/cols always valid
    bool x0ok = (ix0 >= 0), x3ok = (ix0 + 3 < 128);
    for (int ic = 0; ic < 16; ++ic) {
        const float* xc = xin + ic * 16384 + iy0 * 128 + ix0;
        float p0  = (y0ok && x0ok) ? xc[0]       : 0.f;
        float p1  =  y0ok          ? xc[1]       : 0.f;
        float p2  =  y0ok          ? xc[2]       : 0.f;
        float p3  = (y0ok && x3ok) ? xc[3]       : 0.f;
        float p4  =  x0ok          ? xc[128 + 0] : 0.f;
        float p5  =                  xc[128 + 1];
        float p6  =                  xc[128 + 2];
        float p7  =  x3ok          ? xc[128 + 3] : 0.f;
        float p8  =  x0ok          ? xc[256 + 0] : 0.f;
        float p9  =                  xc[256 + 1];
        float p10 =                  xc[256 + 2];
        float p11 =  x3ok          ? xc[256 + 3] : 0.f;
        float p12 = (y3ok && x0ok) ? xc[384 + 0] : 0.f;
        float p13 =  y3ok          ? xc[384 + 1] : 0.f;
        float p14 =  y3ok          ? xc[384 + 2] : 0.f;
        float p15 = (y3ok && x3ok) ? xc[384 + 3] : 0.f;
        const float* wp = w + ic * 16;
#define FMAOC(oc) { const float* q = wp + oc * 256; \
        a##oc = fmaf(p0,  q[0],  a##oc); a##oc = fmaf(p1,  q[1],  a##oc); \
        a##oc = fmaf(p2,  q[2],  a##oc); a##oc = fmaf(p3,  q[3],  a##oc); \
        a##oc = fmaf(p4,  q[4],  a##oc); a##oc = fmaf(p5,  q[5],  a##oc); \
        a##oc = fmaf(p6,  q[6],  a##oc); a##oc = fmaf(p7,  q[7],  a##oc); \
        a##oc = fmaf(p8,  q[8],  a##oc); a##oc = fmaf(p9,  q[9],  a##oc); \
        a##oc = fmaf(p10, q[10], a##oc); a##oc = fmaf(p11, q[11], a##oc); \
        a##oc = fmaf(p12, q[12], a##oc); a##oc = fmaf(p13, q[13], a##oc); \
        a##oc = fmaf(p14, q[14], a##oc); a##oc = fmaf(p15, q[15], a##oc); }
        R16(FMAOC)
#undef FMAOC
    }
    float* o = out + (size_t)b * (16 * 4096) + oy * 64 + ox;
#define STO(oc) o[oc * 4096] = fmaxf(a##oc, 0.f);
    R16(STO)
#undef STO
}

// ---------------- residual block: out = in + relu(conv3x3(in)) — named scalars, 2 px/thread ----------------
__global__ __launch_bounds__(256, 2) void res_k(const float* __restrict__ in, const float* __restrict__ w,
                                                const float* __restrict__ bias, float* __restrict__ out) {
    int b    = blockIdx.x >> 3;
    int ty   = (blockIdx.x & 7) * 8;
    int row  = threadIdx.x >> 5;
    int col2 = threadIdx.x & 31;
    int oy   = ty + row;
    int ox0  = col2 * 2;
    const float* xin = in + (size_t)b * 65536;
#define DECLB(i) float b0_##i = bias[i], b1_##i = bias[i];
    R16(DECLB)
#undef DECLB
    bool yt = (oy > 0), yb = (oy < 63);
    bool xl = (ox0 > 0), xr = (ox0 < 62);
    for (int ic = 0; ic < 16; ++ic) {
        const float* xb = xin + ic * 4096 + (oy - 1) * 64 + ox0 - 1;
        float pa0 = (yt && xl) ? xb[0]       : 0.f;
        float pa1 =  yt        ? xb[1]       : 0.f;
        float pa2 =  yt        ? xb[2]       : 0.f;
        float pa3 = (yt && xr) ? xb[3]       : 0.f;
        float pb0 =  xl        ? xb[64 + 0]  : 0.f;
        float pb1 =              xb[64 + 1];
        float pb2 =              xb[64 + 2];
        float pb3 =  xr        ? xb[64 + 3]  : 0.f;
        float pc0 = (yb && xl) ? xb[128 + 0] : 0.f;
        float pc1 =  yb        ? xb[128 + 1] : 0.f;
        float pc2 =  yb        ? xb[128 + 2] : 0.f;
        float pc3 = (yb && xr) ? xb[128 + 3] : 0.f;
        const float* wp = w + ic * 9;
#define FMAR(oc) { const float* q = wp + oc * 144; \
        b0_##oc = fmaf(pa0, q[0], b0_##oc); b1_##oc = fmaf(pa1, q[0], b1_##oc); \
        b0_##oc = fmaf(pa1, q[1], b0_##oc); b1_##oc = fmaf(pa2, q[1], b1_##oc); \
        b0_##oc = fmaf(pa2, q[2], b0_##oc); b1_##oc = fmaf(pa3, q[2], b1_##oc); \
        b0_##oc = fmaf(pb0, q[3], b0_##oc); b1_##oc = fmaf(pb1, q[3], b1_##oc); \
        b0_##oc = fmaf(pb1, q[4], b0_##oc); b1_##oc = fmaf(pb2, q[4], b1_##oc); \
        b0_##oc = fmaf(pb2, q[5], b0_##oc); b1_##oc = fmaf(pb3, q[5], b1_##oc); \
        b0_##oc = fmaf(pc0, q[6], b0_##oc); b1_##oc = fmaf(pc1, q[6], b1_##oc); \
        b0_##oc = fmaf(pc1, q[7], b0_##oc); b1_##oc = fmaf(pc2, q[7], b1_##oc); \
        b0_##oc = fmaf(pc2, q[8], b0_##oc); b1_##oc = fmaf(pc3, q[8], b1_##oc); }
        R16(FMAR)
#undef FMAR
    }
    float* o        = out + (size_t)b * 65536 + oy * 64 + ox0;
    const float* rr = xin + oy * 64 + ox0;
#define RSTO(oc) { float2 rv = *(const float2*)(rr + oc * 4096); float2 ov; \
        ov.x = rv.x + fmaxf(b0_##oc, 0.f); ov.y = rv.y + fmaxf(b1_##oc, 0.f); \
        *(float2*)(o + oc * 4096) = ov; }
    R16(RSTO)
#undef RSTO
}

// ---------------- VQ: rows of 16 contiguous floats (raw NCHW flatten), K=64 ----------------
__global__ __launch_bounds__(256) void vq_k(const float* __restrict__ h, const float* __restrict__ cb,
                                            float* __restrict__ q, float* __restrict__ idx_out) {
    __shared__ float cbs[1024];  // 64 x 16
    __shared__ float cn[64];
    for (int i = threadIdx.x; i < 1024; i += 256) cbs[i] = cb[i];
    __syncthreads();
    if (threadIdx.x < 64) {
        float s = 0.f;
#pragma unroll
        for (int d = 0; d < 16; ++d) { float v = cbs[threadIdx.x * 16 + d]; s = fmaf(v, v, s); }
        cn[threadIdx.x] = s;
    }
    __syncthreads();
    int r = blockIdx.x * 256 + threadIdx.x;   // 262144 rows
    float f[16];
    const float4* hp = (const float4*)(h + (size_t)r * 16);
#pragma unroll
    for (int j = 0; j < 4; ++j) {
        float4 v = hp[j];
        f[j * 4 + 0] = v.x; f[j * 4 + 1] = v.y; f[j * 4 + 2] = v.z; f[j * 4 + 3] = v.w;
    }
    float best = 3.4e38f;
    int bi = 0;
    for (int k = 0; k < 64; ++k) {
        float dot = 0.f;
#pragma unroll
        for (int d = 0; d < 16; ++d) dot = fmaf(f[d], cbs[k * 16 + d], dot);
        float dist = cn[k] - 2.f * dot;   // +||f||^2 is per-row constant, argmin-invariant
        if (dist < best) { best = dist; bi = k; }
    }
    float4* qp = (float4*)(q + (size_t)r * 16);
    const float4* cp = (const float4*)(cbs + bi * 16);
#pragma unroll
    for (int j = 0; j < 4; ++j) qp[j] = cp[j];
    idx_out[r] = (float)bi;
}

// ---------------- tconv1: ConvTranspose2d 16->16, k4 s2 p1, 64->128, relu — named scalars ----------------
// Row-pair: dy compile-time outer; t0_*/t1_* named accumulators; parity-literal weight idx -> SGPR.
// Zero LDS; channel-last coalesced 128B/lane stores.
__global__ __launch_bounds__(256, 2) void tconv1_k(const float* __restrict__ in,
                                                   const float* __restrict__ w1, const float* __restrict__ bia,
                                                   float* __restrict__ out) {
    int idx = blockIdx.x * 256 + threadIdx.x;   // 64 img * 64*64 quads
    int v = idx & 63;                            // quad col (output cols 2v, 2v+1)
    int u = (idx >> 6) & 63;                     // quad row
    int b = idx >> 12;
    const float* xin = in + (size_t)b * 65536;   // (16,64,64) channel-first
    bool xlok = (v > 0), xrok = (v < 63);

#pragma unroll
    for (int dy = 0; dy < 2; ++dy) {
#define TDECL(oc) float t0_##oc = bia[oc], t1_##oc = bia[oc];
        R16(TDECL)
#undef TDECL
        for (int ic = 0; ic < 16; ++ic) {
            const float* xc = xin + ic * 4096;
            int jy0 = u + dy - 1;                // row r=0
            int jy1 = u + dy;                    // row r=1
            bool y0ok = (jy0 >= 0 && jy0 < 64);
            bool y1ok = (jy1 < 64);
            const float* r0 = xc + jy0 * 64 + v - 1;
            const float* r1 = xc + jy1 * 64 + v - 1;
            float v00 = (y0ok && xlok) ? r0[0] : 0.f;
            float v01 =  y0ok          ? r0[1] : 0.f;
            float v02 = (y0ok && xrok) ? r0[2] : 0.f;
            float v10 = (y1ok && xlok) ? r1[0] : 0.f;
            float v11 =  y1ok          ? r1[1] : 0.f;
            float v12 = (y1ok && xrok) ? r1[2] : 0.f;
            const float* wic = w1 + ic * 256;    // (ic,oc,4,4)
#define TFMA(oc) { const float* q = wic + oc * 16; \
            t0_##oc = fmaf(v11, q[(1 - dy) * 4 + 1], t0_##oc); \
            t0_##oc = fmaf(v10, q[(1 - dy) * 4 + 3], t0_##oc); \
            t0_##oc = fmaf(v01, q[(3 - dy) * 4 + 1], t0_##oc); \
            t0_##oc = fmaf(v00, q[(3 - dy) * 4 + 3], t0_##oc); \
            t1_##oc = fmaf(v12, q[(1 - dy) * 4 + 0], t1_##oc); \
            t1_##oc = fmaf(v11, q[(1 - dy) * 4 + 2], t1_##oc); \
            t1_##oc = fmaf(v02, q[(3 - dy) * 4 + 0], t1_##oc); \
            t1_##oc = fmaf(v01, q[(3 - dy) * 4 + 2], t1_##oc); }
            R16(TFMA)
#undef TFMA
        }
        int my = 2 * u + dy;
        float4* o = (float4*)(out + (((size_t)b * 16384) + my * 128 + 2 * v) * 16);
        float4 s;
        s.x = fmaxf(t0_0,  0.f); s.y = fmaxf(t0_1,  0.f); s.z = fmaxf(t0_2,  0.f); s.w = fmaxf(t0_3,  0.f); o[0] = s;
        s.x = fmaxf(t0_4,  0.f); s.y = fmaxf(t0_5,  0.f); s.z = fmaxf(t0_6,  0.f); s.w = fmaxf(t0_7,  0.f); o[1] = s;
        s.x = fmaxf(t0_8,  0.f); s.y = fmaxf(t0_9,  0.f); s.z = fmaxf(t0_10, 0.f); s.w = fmaxf(t0_11, 0.f); o[2] = s;
        s.x = fmaxf(t0_12, 0.f); s.y = fmaxf(t0_13, 0.f); s.z = fmaxf(t0_14, 0.f); s.w = fmaxf(t0_15, 0.f); o[3] = s;
        s.x = fmaxf(t1_0,  0.f); s.y = fmaxf(t1_1,  0.f); s.z = fmaxf(t1_2,  0.f); s.w = fmaxf(t1_3,  0.f); o[4] = s;
        s.x = fmaxf(t1_4,  0.f); s.y = fmaxf(t1_5,  0.f); s.z = fmaxf(t1_6,  0.f); s.w = fmaxf(t1_7,  0.f); o[5] = s;
        s.x = fmaxf(t1_8,  0.f); s.y = fmaxf(t1_9,  0.f); s.z = fmaxf(t1_10, 0.f); s.w = fmaxf(t1_11, 0.f); o[6] = s;
        s.x = fmaxf(t1_12, 0.f); s.y = fmaxf(t1_13, 0.f); s.z = fmaxf(t1_14, 0.f); s.w = fmaxf(t1_15, 0.f); o[7] = s;
    }
}

// ---------------- tconv2: ConvTranspose2d 16->1, k4 s2 p1, 128->256 ----------------
#define P2 20
__global__ __launch_bounds__(256) void tconv2_k(const float* __restrict__ f1,
                                                const float* __restrict__ w2, const float* __restrict__ b2,
                                                float* __restrict__ out) {
    __shared__ float s1[324 * P2];       // [pixel(18x18)][16 ch + pad4]
    __shared__ float ws2[256];           // (ic,1,4,4)
    __shared__ float b2s;
    if (threadIdx.x < 256) ws2[threadIdx.x] = w2[threadIdx.x];
    if (threadIdx.x == 0) b2s = b2[0];

    int tile = blockIdx.x & 63;
    int b    = blockIdx.x >> 6;
    int Y0 = (tile >> 3) * 32;
    int X0 = (tile & 7) * 32;
    int m0 = (Y0 >> 1) - 1;
    int n0 = (X0 >> 1) - 1;
    const float* fb = f1 + (size_t)b * 262144;   // (128,128,16) channel-last

    for (int i = threadIdx.x; i < 5184; i += 256) {
        int p  = i >> 4;
        int ic = i & 15;
        int my = m0 + p / 18;
        int mx = n0 + p % 18;
        float v = 0.f;
        if (my >= 0 && my < 128 && mx >= 0 && mx < 128)
            v = fb[((size_t)(my * 128 + mx)) * 16 + ic];
        s1[p * P2 + ic] = v;
    }
    __syncthreads();

    int ly0 = threadIdx.x >> 5;
    int lx  = threadIdx.x & 31;
    int gx  = X0 + lx;
    int kyb = (Y0 + ly0 + 1) & 1;
    int kxb = (gx + 1) & 1;
    float wr[2][2][16];
#pragma unroll
    for (int a = 0; a < 2; ++a) {
#pragma unroll
        for (int c = 0; c < 2; ++c) {
            int ky = kyb + 2 * a, kx = kxb + 2 * c;
#pragma unroll
            for (int ic = 0; ic < 16; ++ic)
                wr[a][c][ic] = ws2[ic * 16 + ky * 4 + kx];
        }
    }
    int sx[2];
#pragma unroll
    for (int c = 0; c < 2; ++c) sx[c] = ((gx + 1 - (kxb + 2 * c)) >> 1) - n0;

#pragma unroll
    for (int r = 0; r < 4; ++r) {
        int gy = Y0 + ly0 + 8 * r;
        float acc = b2s;
#pragma unroll
        for (int a = 0; a < 2; ++a) {
            int sy = ((gy + 1 - (kyb + 2 * a)) >> 1) - m0;
#pragma unroll
            for (int c = 0; c < 2; ++c) {
                const float4* sp4 = (const float4*)&s1[(sy * 18 + sx[c]) * P2];
#pragma unroll
                for (int j = 0; j < 4; ++j) {
                    float4 v = sp4[j];
                    acc = fmaf(v.x, wr[a][c][j * 4 + 0], acc);
                    acc = fmaf(v.y, wr[a][c][j * 4 + 1], acc);
                    acc = fmaf(v.z, wr[a][c][j * 4 + 2], acc);
                    acc = fmaf(v.w, wr[a][c][j * 4 + 3], acc);
                }
            }
        }
        out[(size_t)b * 65536 + gy * 256 + gx] = acc;
    }
}

extern "C" void kernel_launch(void* const* d_in, const int* in_sizes, int n_in,
                              void* d_out, int out_size, void* d_ws, size_t ws_size,
                              hipStream_t stream) {
    const float* x    = (const float*)d_in[0];
    const float* c1w  = (const float*)d_in[1];
    const float* c1b  = (const float*)d_in[2];
    const float* c2w  = (const float*)d_in[3];
    const float* c2b  = (const float*)d_in[4];
    const float* er1w = (const float*)d_in[5];
    const float* er1b = (const float*)d_in[6];
    const float* er2w = (const float*)d_in[7];
    const float* er2b = (const float*)d_in[8];
    const float* cb   = (const float*)d_in[9];
    const float* dr1w = (const float*)d_in[10];
    const float* dr1b = (const float*)d_in[11];
    const float* dr2w = (const float*)d_in[12];
    const float* dr2b = (const float*)d_in[13];
    const float* t1w  = (const float*)d_in[14];
    const float* t1b  = (const float*)d_in[15];
    const float* t2w  = (const float*)d_in[16];
    const float* t2b  = (const float*)d_in[17];

    float* f1 = (float*)d_ws;                                // 64 MiB: dec ch-last
    float* f2 = (float*)((char*)d_ws + 67108864);            // (64,16,64,64)
    float* f3 = (float*)((char*)d_ws + 67108864 + 16777216); // (64,16,64,64)

    float* out     = (float*)d_out;                          // decoded: 4,194,304 f32
    float* idx_out = out + 4194304;                          // indices: 262,144 f32

    conv1_k <<<4096, 256, 0, stream>>>(x, c1w, c1b, f1);
    conv2_k <<<1024, 256, 0, stream>>>(f1, c2w, c2b, f2);
    res_k   <<< 512, 256, 0, stream>>>(f2, er1w, er1b, f3);  // er1
    res_k   <<< 512, 256, 0, stream>>>(f3, er2w, er2b, f2);  // er2
    vq_k    <<<1024, 256, 0, stream>>>(f2, cb, f3, idx_out); // quantized -> f3
    res_k   <<< 512, 256, 0, stream>>>(f3, dr1w, dr1b, f2);  // dr1
    res_k   <<< 512, 256, 0, stream>>>(f2, dr2w, dr2b, f3);  // dr2
    tconv1_k<<<1024, 256, 0, stream>>>(f3, t1w, t1b, f1);
    tconv2_k<<<4096, 256, 0, stream>>>(f1, t2w, t2b, out);
}

// Round 15
// 315.292 us; speedup vs baseline: 1.0884x; 1.0884x over previous
//
#include <hip/hip_runtime.h>
#include <hip/hip_bf16.h>

// VQ-VAE forward, B=64, F=16.  ALL I/O float32 (d_out = float*: decoded 4194304 f32, indices 262144 f32).
// ws layout: f1 (64 MiB) | f2 (16 MiB) | f3 (16 MiB) = 96 MiB.
// R15: occupancy-first. tconv1 parity-split via block-uniform template branch (2048 blocks,
//      32 acc/thread); conv2 oc-halved (2048 blocks, 8 acc); res 1px/thread (1024 blocks).
//      Rationale: VALUBusy*dur == pure FMA time on all slow kernels -> latency-stall-bound at
//      2-4 waves/SIMD; conv1 (8 waves/SIMD, small state) is the only healthy kernel. TLP > ILP here.
// Lessons: stage once barrier once (R8); uniform weights -> SGPR not LDS (R10);
//          allocator targets tiny VGPR regardless of launch_bounds/naming (R13/R14) -> give it waves.

#define R16(M) M(0) M(1) M(2) M(3) M(4) M(5) M(6) M(7) M(8) M(9) M(10) M(11) M(12) M(13) M(14) M(15)
#define R8(M)  M(0) M(1) M(2) M(3) M(4) M(5) M(6) M(7)

// ---------------- conv1: 1->16, 256->128 (healthy: 16 blocks/CU) ----------------
__global__ __launch_bounds__(256) void conv1_k(const float* __restrict__ x, const float* __restrict__ w,
                                               const float* __restrict__ bias, float* __restrict__ out) {
    int idx = blockIdx.x * 256 + threadIdx.x;   // 64*128*128
    int ox = idx & 127;
    int oy = (idx >> 7) & 127;
    int b  = idx >> 14;
    const float* xin = x + (size_t)b * 65536;
    float pv[16];
#pragma unroll
    for (int ky = 0; ky < 4; ++ky) {
        int iy = 2 * oy - 1 + ky;
#pragma unroll
        for (int kx = 0; kx < 4; ++kx) {
            int ix = 2 * ox - 1 + kx;
            pv[ky * 4 + kx] = (iy >= 0 && iy < 256 && ix >= 0 && ix < 256)
                                  ? xin[iy * 256 + ix] : 0.f;
        }
    }
    float* o = out + (size_t)b * (16 * 16384) + oy * 128 + ox;
#pragma unroll
    for (int oc = 0; oc < 16; ++oc) {
        float acc = bias[oc];
#pragma unroll
        for (int k = 0; k < 16; ++k) acc = fmaf(pv[k], w[oc * 16 + k], acc);
        o[oc * 16384] = fmaxf(acc, 0.f);
    }
}

// ---------------- conv2: 16->16, 128->64 — oc-halved, 2048 blocks (8/CU) ----------------
__global__ __launch_bounds__(256) void conv2_k(const float* __restrict__ in, const float* __restrict__ w,
                                               const float* __restrict__ bias, float* __restrict__ out) {
    int half = blockIdx.x >> 10;                 // high-bit split: halves temporally apart (L3 reuse)
    int idx  = (blockIdx.x & 1023) * 256 + threadIdx.x;   // 64*64*64
    int ox = idx & 63;
    int oy = (idx >> 6) & 63;
    int b  = idx >> 12;
    int ocb = half * 8;
    const float* xin = in + (size_t)b * (16 * 16384);
    const float* wb  = w + ocb * 256;
#define DECLA(i) float a##i = bias[ocb + i];
    R8(DECLA)
#undef DECLA
    int iy0 = 2 * oy - 1, ix0 = 2 * ox - 1;
    bool y0ok = (iy0 >= 0), y3ok = (iy0 + 3 < 128);
    bool x0ok = (ix0 >= 0), x3ok = (ix0 + 3 < 128);
    for (int ic = 0; ic < 16; ++ic) {
        const float* xc = xin + ic * 16384 + iy0 * 128 + ix0;
        float p0  = (y0ok && x0ok) ? xc[0]       : 0.f;
        float p1  =  y0ok          ? xc[1]       : 0.f;
        float p2  =  y0ok          ? xc[2]       : 0.f;
        float p3  = (y0ok && x3ok) ? xc[3]       : 0.f;
        float p4  =  x0ok          ? xc[128 + 0] : 0.f;
        float p5  =                  xc[128 + 1];
        float p6  =                  xc[128 + 2];
        float p7  =  x3ok          ? xc[128 + 3] : 0.f;
        float p8  =  x0ok          ? xc[256 + 0] : 0.f;
        float p9  =                  xc[256 + 1];
        float p10 =                  xc[256 + 2];
        float p11 =  x3ok          ? xc[256 + 3] : 0.f;
        float p12 = (y3ok && x0ok) ? xc[384 + 0] : 0.f;
        float p13 =  y3ok          ? xc[384 + 1] : 0.f;
        float p14 =  y3ok          ? xc[384 + 2] : 0.f;
        float p15 = (y3ok && x3ok) ? xc[384 + 3] : 0.f;
        const float* wp = wb + ic * 16;
#define FMAOC(oc) { const float* q = wp + oc * 256; \
        a##oc = fmaf(p0,  q[0],  a##oc); a##oc = fmaf(p1,  q[1],  a##oc); \
        a##oc = fmaf(p2,  q[2],  a##oc); a##oc = fmaf(p3,  q[3],  a##oc); \
        a##oc = fmaf(p4,  q[4],  a##oc); a##oc = fmaf(p5,  q[5],  a##oc); \
        a##oc = fmaf(p6,  q[6],  a##oc); a##oc = fmaf(p7,  q[7],  a##oc); \
        a##oc = fmaf(p8,  q[8],  a##oc); a##oc = fmaf(p9,  q[9],  a##oc); \
        a##oc = fmaf(p10, q[10], a##oc); a##oc = fmaf(p11, q[11], a##oc); \
        a##oc = fmaf(p12, q[12], a##oc); a##oc = fmaf(p13, q[13], a##oc); \
        a##oc = fmaf(p14, q[14], a##oc); a##oc = fmaf(p15, q[15], a##oc); }
        R8(FMAOC)
#undef FMAOC
    }
    float* o = out + (size_t)b * (16 * 4096) + (size_t)ocb * 4096 + oy * 64 + ox;
#define STO(oc) o[oc * 4096] = fmaxf(a##oc, 0.f);
    R8(STO)
#undef STO
}

// ---------------- residual block: out = in + relu(conv3x3(in)) — 1 px/thread, 1024 blocks ----------------
__global__ __launch_bounds__(256) void res_k(const float* __restrict__ in, const float* __restrict__ w,
                                             const float* __restrict__ bias, float* __restrict__ out) {
    int idx = blockIdx.x * 256 + threadIdx.x;   // 64*64*64
    int ox = idx & 63;
    int oy = (idx >> 6) & 63;
    int b  = idx >> 12;
    const float* xin = in + (size_t)b * 65536;
#define DECLB(i) float a##i = bias[i];
    R16(DECLB)
#undef DECLB
    bool yt = (oy > 0), yb = (oy < 63);
    bool xl = (ox > 0), xr = (ox < 63);
    for (int ic = 0; ic < 16; ++ic) {
        const float* xb = xin + ic * 4096 + (oy - 1) * 64 + (ox - 1);
        float pa0 = (yt && xl) ? xb[0]       : 0.f;
        float pa1 =  yt        ? xb[1]       : 0.f;
        float pa2 = (yt && xr) ? xb[2]       : 0.f;
        float pb0 =  xl        ? xb[64 + 0]  : 0.f;
        float pb1 =              xb[64 + 1];
        float pb2 =  xr        ? xb[64 + 2]  : 0.f;
        float pc0 = (yb && xl) ? xb[128 + 0] : 0.f;
        float pc1 =  yb        ? xb[128 + 1] : 0.f;
        float pc2 = (yb && xr) ? xb[128 + 2] : 0.f;
        const float* wp = w + ic * 9;
#define FMAR(oc) { const float* q = wp + oc * 144; \
        a##oc = fmaf(pa0, q[0], a##oc); a##oc = fmaf(pa1, q[1], a##oc); a##oc = fmaf(pa2, q[2], a##oc); \
        a##oc = fmaf(pb0, q[3], a##oc); a##oc = fmaf(pb1, q[4], a##oc); a##oc = fmaf(pb2, q[5], a##oc); \
        a##oc = fmaf(pc0, q[6], a##oc); a##oc = fmaf(pc1, q[7], a##oc); a##oc = fmaf(pc2, q[8], a##oc); }
        R16(FMAR)
#undef FMAR
    }
    float* o        = out + (size_t)b * 65536 + oy * 64 + ox;
    const float* rr = xin + oy * 64 + ox;
#define RSTO(oc) o[oc * 4096] = rr[oc * 4096] + fmaxf(a##oc, 0.f);
    R16(RSTO)
#undef RSTO
}

// ---------------- VQ: rows of 16 contiguous floats (raw NCHW flatten), K=64 ----------------
__global__ __launch_bounds__(256) void vq_k(const float* __restrict__ h, const float* __restrict__ cb,
                                            float* __restrict__ q, float* __restrict__ idx_out) {
    __shared__ float cbs[1024];  // 64 x 16
    __shared__ float cn[64];
    for (int i = threadIdx.x; i < 1024; i += 256) cbs[i] = cb[i];
    __syncthreads();
    if (threadIdx.x < 64) {
        float s = 0.f;
#pragma unroll
        for (int d = 0; d < 16; ++d) { float v = cbs[threadIdx.x * 16 + d]; s = fmaf(v, v, s); }
        cn[threadIdx.x] = s;
    }
    __syncthreads();
    int r = blockIdx.x * 256 + threadIdx.x;   // 262144 rows
    float f[16];
    const float4* hp = (const float4*)(h + (size_t)r * 16);
#pragma unroll
    for (int j = 0; j < 4; ++j) {
        float4 v = hp[j];
        f[j * 4 + 0] = v.x; f[j * 4 + 1] = v.y; f[j * 4 + 2] = v.z; f[j * 4 + 3] = v.w;
    }
    float best = 3.4e38f;
    int bi = 0;
    for (int k = 0; k < 64; ++k) {
        float dot = 0.f;
#pragma unroll
        for (int d = 0; d < 16; ++d) dot = fmaf(f[d], cbs[k * 16 + d], dot);
        float dist = cn[k] - 2.f * dot;   // +||f||^2 is per-row constant, argmin-invariant
        if (dist < best) { best = dist; bi = k; }
    }
    float4* qp = (float4*)(q + (size_t)r * 16);
    const float4* cp = (const float4*)(cbs + bi * 16);
#pragma unroll
    for (int j = 0; j < 4; ++j) qp[j] = cp[j];
    idx_out[r] = (float)bi;
}

// ---------------- tconv1: ConvTranspose2d 16->16, k4 s2 p1, 64->128, relu ----------------
// Parity-split: blockIdx.x&1 = dy (block-uniform template branch). Per-thread: one output row
// pair (my=2u+dy; mx=2v,2v+1), 32 named acc. Weight idx parity-literal -> SGPR. 2048 blocks (8/CU).
template <int DY>
__device__ __forceinline__ void tconv1_body(const float* __restrict__ xin, const float* __restrict__ w1,
                                            const float* __restrict__ bia, float* __restrict__ out,
                                            int b, int u, int v, bool xlok, bool xrok) {
#define TDECL(oc) float t0_##oc = bia[oc], t1_##oc = bia[oc];
    R16(TDECL)
#undef TDECL
    for (int ic = 0; ic < 16; ++ic) {
        const float* xc = xin + ic * 4096;
        int jy0 = u + DY - 1;
        int jy1 = u + DY;
        bool y0ok = (jy0 >= 0 && jy0 < 64);
        bool y1ok = (jy1 < 64);
        const float* r0 = xc + jy0 * 64 + v - 1;
        const float* r1 = xc + jy1 * 64 + v - 1;
        float v00 = (y0ok && xlok) ? r0[0] : 0.f;
        float v01 =  y0ok          ? r0[1] : 0.f;
        float v02 = (y0ok && xrok) ? r0[2] : 0.f;
        float v10 = (y1ok && xlok) ? r1[0] : 0.f;
        float v11 =  y1ok          ? r1[1] : 0.f;
        float v12 = (y1ok && xrok) ? r1[2] : 0.f;
        const float* wic = w1 + ic * 256;    // (ic,oc,4,4)
#define TFMA(oc) { const float* q = wic + oc * 16; \
        t0_##oc = fmaf(v11, q[(1 - DY) * 4 + 1], t0_##oc); \
        t0_##oc = fmaf(v10, q[(1 - DY) * 4 + 3], t0_##oc); \
        t0_##oc = fmaf(v01, q[(3 - DY) * 4 + 1], t0_##oc); \
        t0_##oc = fmaf(v00, q[(3 - DY) * 4 + 3], t0_##oc); \
        t1_##oc = fmaf(v12, q[(1 - DY) * 4 + 0], t1_##oc); \
        t1_##oc = fmaf(v11, q[(1 - DY) * 4 + 2], t1_##oc); \
        t1_##oc = fmaf(v02, q[(3 - DY) * 4 + 0], t1_##oc); \
        t1_##oc = fmaf(v01, q[(3 - DY) * 4 + 2], t1_##oc); }
        R16(TFMA)
#undef TFMA
    }
    int my = 2 * u + DY;
    float4* o = (float4*)(out + (((size_t)b * 16384) + my * 128 + 2 * v) * 16);
    float4 s;
    s.x = fmaxf(t0_0,  0.f); s.y = fmaxf(t0_1,  0.f); s.z = fmaxf(t0_2,  0.f); s.w = fmaxf(t0_3,  0.f); o[0] = s;
    s.x = fmaxf(t0_4,  0.f); s.y = fmaxf(t0_5,  0.f); s.z = fmaxf(t0_6,  0.f); s.w = fmaxf(t0_7,  0.f); o[1] = s;
    s.x = fmaxf(t0_8,  0.f); s.y = fmaxf(t0_9,  0.f); s.z = fmaxf(t0_10, 0.f); s.w = fmaxf(t0_11, 0.f); o[2] = s;
    s.x = fmaxf(t0_12, 0.f); s.y = fmaxf(t0_13, 0.f); s.z = fmaxf(t0_14, 0.f); s.w = fmaxf(t0_15, 0.f); o[3] = s;
    s.x = fmaxf(t1_0,  0.f); s.y = fmaxf(t1_1,  0.f); s.z = fmaxf(t1_2,  0.f); s.w = fmaxf(t1_3,  0.f); o[4] = s;
    s.x = fmaxf(t1_4,  0.f); s.y = fmaxf(t1_5,  0.f); s.z = fmaxf(t1_6,  0.f); s.w = fmaxf(t1_7,  0.f); o[5] = s;
    s.x = fmaxf(t1_8,  0.f); s.y = fmaxf(t1_9,  0.f); s.z = fmaxf(t1_10, 0.f); s.w = fmaxf(t1_11, 0.f); o[6] = s;
    s.x = fmaxf(t1_12, 0.f); s.y = fmaxf(t1_13, 0.f); s.z = fmaxf(t1_14, 0.f); s.w = fmaxf(t1_15, 0.f); o[7] = s;
}

__global__ __launch_bounds__(256) void tconv1_k(const float* __restrict__ in,
                                                const float* __restrict__ w1, const float* __restrict__ bia,
                                                float* __restrict__ out) {
    int dy  = blockIdx.x & 1;                    // block-uniform
    int idx = (blockIdx.x >> 1) * 256 + threadIdx.x;   // 64 img * 64 u * 64 v
    int v = idx & 63;
    int u = (idx >> 6) & 63;
    int b = idx >> 12;
    const float* xin = in + (size_t)b * 65536;   // (16,64,64) channel-first
    bool xlok = (v > 0), xrok = (v < 63);
    if (dy == 0) tconv1_body<0>(xin, w1, bia, out, b, u, v, xlok, xrok);
    else         tconv1_body<1>(xin, w1, bia, out, b, u, v, xlok, xrok);
}

// ---------------- tconv2: ConvTranspose2d 16->1, k4 s2 p1, 128->256 ----------------
#define P2 20
__global__ __launch_bounds__(256) void tconv2_k(const float* __restrict__ f1,
                                                const float* __restrict__ w2, const float* __restrict__ b2,
                                                float* __restrict__ out) {
    __shared__ float s1[324 * P2];       // [pixel(18x18)][16 ch + pad4]
    __shared__ float ws2[256];           // (ic,1,4,4)
    __shared__ float b2s;
    if (threadIdx.x < 256) ws2[threadIdx.x] = w2[threadIdx.x];
    if (threadIdx.x == 0) b2s = b2[0];

    int tile = blockIdx.x & 63;
    int b    = blockIdx.x >> 6;
    int Y0 = (tile >> 3) * 32;
    int X0 = (tile & 7) * 32;
    int m0 = (Y0 >> 1) - 1;
    int n0 = (X0 >> 1) - 1;
    const float* fb = f1 + (size_t)b * 262144;   // (128,128,16) channel-last

    for (int i = threadIdx.x; i < 5184; i += 256) {
        int p  = i >> 4;
        int ic = i & 15;
        int my = m0 + p / 18;
        int mx = n0 + p % 18;
        float v = 0.f;
        if (my >= 0 && my < 128 && mx >= 0 && mx < 128)
            v = fb[((size_t)(my * 128 + mx)) * 16 + ic];
        s1[p * P2 + ic] = v;
    }
    __syncthreads();

    int ly0 = threadIdx.x >> 5;
    int lx  = threadIdx.x & 31;
    int gx  = X0 + lx;
    int kyb = (Y0 + ly0 + 1) & 1;
    int kxb = (gx + 1) & 1;
    float wr[2][2][16];
#pragma unroll
    for (int a = 0; a < 2; ++a) {
#pragma unroll
        for (int c = 0; c < 2; ++c) {
            int ky = kyb + 2 * a, kx = kxb + 2 * c;
#pragma unroll
            for (int ic = 0; ic < 16; ++ic)
                wr[a][c][ic] = ws2[ic * 16 + ky * 4 + kx];
        }
    }
    int sx[2];
#pragma unroll
    for (int c = 0; c < 2; ++c) sx[c] = ((gx + 1 - (kxb + 2 * c)) >> 1) - n0;

#pragma unroll
    for (int r = 0; r < 4; ++r) {
        int gy = Y0 + ly0 + 8 * r;
        float acc = b2s;
#pragma unroll
        for (int a = 0; a < 2; ++a) {
            int sy = ((gy + 1 - (kyb + 2 * a)) >> 1) - m0;
#pragma unroll
            for (int c = 0; c < 2; ++c) {
                const float4* sp4 = (const float4*)&s1[(sy * 18 + sx[c]) * P2];
#pragma unroll
                for (int j = 0; j < 4; ++j) {
                    float4 v = sp4[j];
                    acc = fmaf(v.x, wr[a][c][j * 4 + 0], acc);
                    acc = fmaf(v.y, wr[a][c][j * 4 + 1], acc);
                    acc = fmaf(v.z, wr[a][c][j * 4 + 2], acc);
                    acc = fmaf(v.w, wr[a][c][j * 4 + 3], acc);
                }
            }
        }
        out[(size_t)b * 65536 + gy * 256 + gx] = acc;
    }
}

extern "C" void kernel_launch(void* const* d_in, const int* in_sizes, int n_in,
                              void* d_out, int out_size, void* d_ws, size_t ws_size,
                              hipStream_t stream) {
    const float* x    = (const float*)d_in[0];
    const float* c1w  = (const float*)d_in[1];
    const float* c1b  = (const float*)d_in[2];
    const float* c2w  = (const float*)d_in[3];
    const float* c2b  = (const float*)d_in[4];
    const float* er1w = (const float*)d_in[5];
    const float* er1b = (const float*)d_in[6];
    const float* er2w = (const float*)d_in[7];
    const float* er2b = (const float*)d_in[8];
    const float* cb   = (const float*)d_in[9];
    const float* dr1w = (const float*)d_in[10];
    const float* dr1b = (const float*)d_in[11];
    const float* dr2w = (const float*)d_in[12];
    const float* dr2b = (const float*)d_in[13];
    const float* t1w  = (const float*)d_in[14];
    const float* t1b  = (const float*)d_in[15];
    const float* t2w  = (const float*)d_in[16];
    const float* t2b  = (const float*)d_in[17];

    float* f1 = (float*)d_ws;                                // 64 MiB: dec ch-last
    float* f2 = (float*)((char*)d_ws + 67108864);            // (64,16,64,64)
    float* f3 = (float*)((char*)d_ws + 67108864 + 16777216); // (64,16,64,64)

    float* out     = (float*)d_out;                          // decoded: 4,194,304 f32
    float* idx_out = out + 4194304;                          // indices: 262,144 f32

    conv1_k <<<4096, 256, 0, stream>>>(x, c1w, c1b, f1);
    conv2_k <<<2048, 256, 0, stream>>>(f1, c2w, c2b, f2);
    res_k   <<<1024, 256, 0, stream>>>(f2, er1w, er1b, f3);  // er1
    res_k   <<<1024, 256, 0, stream>>>(f3, er2w, er2b, f2);  // er2
    vq_k    <<<1024, 256, 0, stream>>>(f2, cb, f3, idx_out); // quantized -> f3
    res_k   <<<1024, 256, 0, stream>>>(f3, dr1w, dr1b, f2);  // dr1
    res_k   <<<1024, 256, 0, stream>>>(f2, dr2w, dr2b, f3);  // dr2
    tconv1_k<<<2048, 256, 0, stream>>>(f3, t1w, t1b, f1);
    tconv2_k<<<4096, 256, 0, stream>>>(f1, t2w, t2b, out);
}